// Round 1
// baseline (180.894 us; speedup 1.0000x reference)
//
#include <hip/hip_runtime.h>

// BeBertEmbedding: out[b,s,d] = pe[s,d]
//                             + (input_ids[b,s]==0 ? W_tok[d,0]+b_tok[d] : 0)
//                             + (segment[b,s]==0   ? W_seg[d,0]+b_seg[d] : 0)
// The reference's where() keeps the gathered embedding ONLY for pad tokens
// (id==0), for which the gathered column is always column 0. Non-pad tokens
// get the constant float(padding_idx)=0.0 vector. So no vocab gather needed.

#define VOCAB 32000
#define DMODEL 768
#define SEQ 2048
#define NB 16
#define D4 (DMODEL / 4)  // 192 float4 per row

// Fold W[:,0] + b into contiguous vectors in workspace (ws is re-poisoned
// to 0xAA before every timed launch, so this must run every call — it's tiny).
__global__ void precompute_vecs(const float* __restrict__ W_tok,
                                const float* __restrict__ b_tok,
                                const float* __restrict__ W_seg,
                                const float* __restrict__ b_seg,
                                float* __restrict__ v) {
    int d = blockIdx.x * blockDim.x + threadIdx.x;
    if (d < DMODEL) {
        v[d]          = W_tok[(size_t)d * VOCAB] + b_tok[d];  // column 0 of W_tok
        v[DMODEL + d] = W_seg[d * 3] + b_seg[d];              // column 0 of W_seg
    }
}

// One block per (b,s) row; 192 threads, one float4 (16B) store per thread.
__global__ __launch_bounds__(192) void embed_kernel(
        const int* __restrict__ ids,
        const int* __restrict__ segs,
        const float* __restrict__ pe,   // [SEQ, DMODEL]
        const float* __restrict__ v,    // [2*DMODEL] precomputed
        float* __restrict__ out) {      // [NB, SEQ, DMODEL]
    const int row = blockIdx.x;         // b*SEQ + s
    const int s = row & (SEQ - 1);
    const int d4 = threadIdx.x;

    const bool t = (ids[row] == 0);     // broadcast load (same addr per block)
    const bool g = (segs[row] == 0);

    const float4* pe4 = (const float4*)pe;
    const float4* vt4 = (const float4*)v;
    const float4* vg4 = (const float4*)(v + DMODEL);

    float4 p  = pe4[s * D4 + d4];
    float4 vt = vt4[d4];                // 3KB, L1/L2 resident
    float4 vg = vg4[d4];

    // Match reference fp add order: (tok + pe) + seg
    float4 o;
    o.x = ((t ? vt.x : 0.0f) + p.x) + (g ? vg.x : 0.0f);
    o.y = ((t ? vt.y : 0.0f) + p.y) + (g ? vg.y : 0.0f);
    o.z = ((t ? vt.z : 0.0f) + p.z) + (g ? vg.z : 0.0f);
    o.w = ((t ? vt.w : 0.0f) + p.w) + (g ? vg.w : 0.0f);

    ((float4*)out)[(size_t)row * D4 + d4] = o;
}

extern "C" void kernel_launch(void* const* d_in, const int* in_sizes, int n_in,
                              void* d_out, int out_size, void* d_ws, size_t ws_size,
                              hipStream_t stream) {
    const int*   ids   = (const int*)d_in[0];
    const int*   segs  = (const int*)d_in[1];
    const float* W_tok = (const float*)d_in[2];
    const float* b_tok = (const float*)d_in[3];
    const float* W_seg = (const float*)d_in[4];
    const float* b_seg = (const float*)d_in[5];
    const float* pe    = (const float*)d_in[6];
    float* out = (float*)d_out;
    float* v   = (float*)d_ws;   // needs 2*768*4 = 6144 bytes

    precompute_vecs<<<3, 256, 0, stream>>>(W_tok, b_tok, W_seg, b_seg, v);
    embed_kernel<<<NB * SEQ, 192, 0, stream>>>(ids, segs, pe, v, out);
}

// Round 3
// 173.693 us; speedup vs baseline: 1.0415x; 1.0415x over previous
//
#include <hip/hip_runtime.h>

// BeBertEmbedding: out[b,s,d] = pe[s,d]
//                             + (input_ids[b,s]==0 ? W_tok[d,0]+b_tok[d] : 0)
//                             + (segment[b,s]==0   ? W_seg[d,0]+b_seg[d] : 0)
// The reference's where() keeps the gathered embedding ONLY for pad tokens
// (id==0), for which the gathered column is always column 0. Non-pad tokens
// get the constant float(padding_idx)=0.0 vector. So no vocab gather needed.
//
// R1 restructure: one block per sequence position s. pe row + folded vectors
// live in registers; loop over the 16 batch rows sharing that s. This reads
// pe exactly once (6 MB total vs 100 MB in R0) and amortizes block setup
// over 48 KB of stores. Output is write-once -> nontemporal stores.
// R2 fix: __builtin_nontemporal_store needs a clang ext_vector_type, not
// HIP's float4 class -> use native vector typedef.

#define VOCAB 32000
#define DMODEL 768
#define SEQ 2048
#define NB 16
#define D4 (DMODEL / 4)  // 192 float4 per row

typedef float f4 __attribute__((ext_vector_type(4)));

// Fold W[:,0] + b into contiguous vectors in workspace (ws is re-poisoned
// to 0xAA before every timed launch, so this must run every call — it's tiny).
__global__ void precompute_vecs(const float* __restrict__ W_tok,
                                const float* __restrict__ b_tok,
                                const float* __restrict__ W_seg,
                                const float* __restrict__ b_seg,
                                float* __restrict__ v) {
    int d = blockIdx.x * blockDim.x + threadIdx.x;
    if (d < DMODEL) {
        v[d]          = W_tok[(size_t)d * VOCAB] + b_tok[d];  // column 0 of W_tok
        v[DMODEL + d] = W_seg[d * 3] + b_seg[d];              // column 0 of W_seg
    }
}

// One block per s in [0,SEQ); 192 threads; each thread owns one float4 lane
// of the embedding row and stores it for all NB batches.
__global__ __launch_bounds__(192) void embed_kernel(
        const int* __restrict__ ids,    // [NB, SEQ]
        const int* __restrict__ segs,   // [NB, SEQ]
        const float* __restrict__ pe,   // [SEQ, DMODEL]
        const float* __restrict__ v,    // [2*DMODEL] precomputed
        float* __restrict__ out) {      // [NB, SEQ, DMODEL]
    const int s  = blockIdx.x;
    const int d4 = threadIdx.x;

    const f4 p  = ((const f4*)pe)[s * D4 + d4];
    const f4 vt = ((const f4*)v)[d4];
    const f4 vg = ((const f4*)(v + DMODEL))[d4];
    const f4 zero = {0.0f, 0.0f, 0.0f, 0.0f};

    // Preload all batch flags (wave-uniform scalar loads, L2-resident).
    bool t[NB], g[NB];
#pragma unroll
    for (int b = 0; b < NB; ++b) {
        t[b] = (ids[b * SEQ + s] == 0);
        g[b] = (segs[b * SEQ + s] == 0);
    }

    f4* o4 = (f4*)out;
#pragma unroll
    for (int b = 0; b < NB; ++b) {
        // Match reference fp add order: (tok + pe) + seg
        f4 o = ((t[b] ? vt : zero) + p) + (g[b] ? vg : zero);
        __builtin_nontemporal_store(o, &o4[((size_t)b * SEQ + s) * D4 + d4]);
    }
}

extern "C" void kernel_launch(void* const* d_in, const int* in_sizes, int n_in,
                              void* d_out, int out_size, void* d_ws, size_t ws_size,
                              hipStream_t stream) {
    const int*   ids   = (const int*)d_in[0];
    const int*   segs  = (const int*)d_in[1];
    const float* W_tok = (const float*)d_in[2];
    const float* b_tok = (const float*)d_in[3];
    const float* W_seg = (const float*)d_in[4];
    const float* b_seg = (const float*)d_in[5];
    const float* pe    = (const float*)d_in[6];
    float* out = (float*)d_out;
    float* v   = (float*)d_ws;   // needs 2*768*4 = 6144 bytes

    precompute_vecs<<<3, 256, 0, stream>>>(W_tok, b_tok, W_seg, b_seg, v);
    embed_kernel<<<SEQ, 192, 0, stream>>>(ids, segs, pe, v, out);
}